// Round 8
// baseline (466.681 us; speedup 1.0000x reference)
//
#include <hip/hip_runtime.h>
#include <cstddef>
#include <cstdint>

#define NN 50000
#define EE 800000
#define ET_ (EE + NN)

typedef __attribute__((ext_vector_type(8))) short bf16x8;
typedef __attribute__((ext_vector_type(4))) float f32x4;

__device__ __forceinline__ float lrelu_(float x) { return x > 0.f ? x : 0.2f * x; }
__device__ __forceinline__ float elu_(float x)   { return x > 0.f ? x : (__expf(x) - 1.f); }
__device__ __forceinline__ short f2bf(float f) {
    unsigned u = __float_as_uint(f);
    unsigned r = (u + 0x7fffu + ((u >> 16) & 1u)) >> 16;
    return (short)r;
}
__device__ __forceinline__ float bflo(unsigned u) { return __uint_as_float(u << 16); }
__device__ __forceinline__ float bfhi(unsigned u) { return __uint_as_float(u & 0xffff0000u); }
__device__ __forceinline__ float bfs(short s) { return __uint_as_float(((unsigned)(unsigned short)s) << 16); }

#define GL16(gp, lp) __builtin_amdgcn_global_load_lds( \
    (const __attribute__((address_space(1))) unsigned int*)(gp), \
    (__attribute__((address_space(3))) unsigned int*)(lp), 16, 0, 0)

// ---------------- fused prep: x->bf16, pack Wt0/Wt1, degree histogram ----------------

__global__ __launch_bounds__(256) void prep_all(const float* __restrict__ x,
                                                const float* __restrict__ cW0, const float* __restrict__ lW0,
                                                const float* __restrict__ cW1, const float* __restrict__ lW1,
                                                const int* __restrict__ ei, int* __restrict__ deg,
                                                short* __restrict__ xb, short* __restrict__ Wt0,
                                                short* __restrict__ Wt1) {
    int i = blockIdx.x * 256 + threadIdx.x;
    if (i < 1600000) {
        float4 v = *(const float4*)(x + (size_t)i * 4);
        short4 o;
        o.x = f2bf(v.x); o.y = f2bf(v.y); o.z = f2bf(v.z); o.w = f2bf(v.w);
        *(short4*)(xb + (size_t)i * 4) = o;
        return;
    }
    i -= 1600000;
    if (i < 512 * 128) {
        int n = i >> 7, k = i & 127;
        float v = (n < 256) ? cW0[k * 256 + n] : lW0[k * 256 + (n - 256)];
        Wt0[i] = f2bf(v);
        return;
    }
    i -= 512 * 128;
    if (i < 512 * 256) {
        int n = i >> 8, k = i & 255;
        float v = (n < 256) ? cW1[k * 256 + n] : lW1[k * 256 + (n - 256)];
        Wt1[i] = f2bf(v);
        return;
    }
    i -= 512 * 256;
    if (i < ET_) {
        int d = (i < EE) ? ei[EE + i] : (i - EE);
        atomicAdd(&deg[d], 1);
    }
}

// ---------------- CSR build ----------------

__global__ __launch_bounds__(1024) void alloc_scan(const int* __restrict__ deg, int* __restrict__ rowptr,
                                                   int* __restrict__ gcnt, int n) {
    __shared__ int s[1024];
    __shared__ int basesh;
    int tid = threadIdx.x;
    int gid = blockIdx.x * 1024 + tid;
    int v = (gid < n) ? deg[gid] : 0;
    s[tid] = v;
    __syncthreads();
    for (int off = 1; off < 1024; off <<= 1) {
        int t = (tid >= off) ? s[tid - off] : 0;
        __syncthreads();
        s[tid] += t;
        __syncthreads();
    }
    if (tid == 1023) basesh = atomicAdd(gcnt, s[1023]);
    __syncthreads();
    if (gid < n) rowptr[gid] = basesh + s[tid] - v;
}

__global__ __launch_bounds__(256) void scatter_k(const int* __restrict__ ei,
                                                 const int* __restrict__ rowptr,
                                                 int* __restrict__ cursor,
                                                 int* __restrict__ csr_src) {
    int e = blockIdx.x * blockDim.x + threadIdx.x;
    if (e >= ET_) return;
    int s, d;
    if (e < EE) { s = ei[e]; d = ei[EE + e]; } else { s = e - EE; d = e - EE; }
    int pos = atomicAdd(&cursor[d], 1);
    csr_src[rowptr[d] + pos] = s;
}

// ---------------- bf16 MFMA GEMM, dbuf + LDS epilogue + fused attn-prep ----------------
// out[M,512] = A[M,K] @ Wt^T ; cols<256 -> XLb (+AS/AD dots), cols>=256 -> Hlinb (+biasLin)

__global__ __launch_bounds__(256) void gemm_bf16(const short* __restrict__ A,
                                                 const short* __restrict__ Wt,
                                                 const float* __restrict__ biasLin,
                                                 const float* __restrict__ attS,
                                                 const float* __restrict__ attD,
                                                 short* __restrict__ XLb,
                                                 short* __restrict__ Hlinb,
                                                 float* __restrict__ AS,
                                                 float* __restrict__ AD,
                                                 int M, int K) {
    __shared__ short smem[4][128 * 32];     // As0|As1|Bs0|Bs1, aliased as C-tile after loop
    const int tid = threadIdx.x;
    const int lane = tid & 63;
    const int wid = tid >> 6;
    const int bm = blockIdx.x * 128;
    const int col0 = blockIdx.y * 128;
    const int wr = wid >> 1, wc = wid & 1;

    f32x4 acc[4][4];
#pragma unroll
    for (int i = 0; i < 4; ++i)
#pragma unroll
        for (int j = 0; j < 4; ++j) acc[i][j] = (f32x4){0.f, 0.f, 0.f, 0.f};

    const int lrow = lane & 15, lk = lane >> 4;

    auto stage = [&](int b, int kk) {
#pragma unroll
        for (int it = 0; it < 2; ++it) {
            const int flat = tid + it * 256;
            const int row = flat >> 2, slot = flat & 3;
            const int ss = slot ^ (row & 3);
            int ar = bm + row; ar = (ar < M) ? ar : (M - 1);
            GL16(A + (size_t)ar * K + kk + ss * 8, &smem[b][flat * 8]);
            GL16(Wt + (size_t)(col0 + row) * K + kk + ss * 8, &smem[2 + b][flat * 8]);
        }
    };

    stage(0, 0);
    int cur = 0;
    for (int k0 = 0; k0 < K; k0 += 32) {
        __syncthreads();
        if (k0 + 32 < K) stage(cur ^ 1, k0 + 32);
        bf16x8 af[4], bfr[4];
#pragma unroll
        for (int mi = 0; mi < 4; ++mi) {
            const int r = wr * 64 + mi * 16 + lrow;
            af[mi] = *(const bf16x8*)(&smem[cur][(r * 4 + (lk ^ (r & 3))) * 8]);
        }
#pragma unroll
        for (int ni = 0; ni < 4; ++ni) {
            const int c = wc * 64 + ni * 16 + lrow;
            bfr[ni] = *(const bf16x8*)(&smem[2 + cur][(c * 4 + (lk ^ (c & 3))) * 8]);
        }
#pragma unroll
        for (int mi = 0; mi < 4; ++mi)
#pragma unroll
            for (int ni = 0; ni < 4; ++ni)
                acc[mi][ni] = __builtin_amdgcn_mfma_f32_16x16x32_bf16(af[mi], bfr[ni], acc[mi][ni], 0, 0, 0);
        cur ^= 1;
    }

    __syncthreads();                        // reuse smem as C-tile [128][128] bf16, XOR-swizzled
    short* Ct = &smem[0][0];
    const bool isLin = (col0 >= 256);
    float bni[4] = {0.f, 0.f, 0.f, 0.f};
    if (isLin) {
#pragma unroll
        for (int ni = 0; ni < 4; ++ni)
            bni[ni] = biasLin[col0 - 256 + wc * 64 + ni * 16 + lrow];
    }
    const int lrow4 = lk * 4;
#pragma unroll
    for (int mi = 0; mi < 4; ++mi) {
#pragma unroll
        for (int ni = 0; ni < 4; ++ni) {
            const int col_l = wc * 64 + ni * 16 + lrow;
#pragma unroll
            for (int rr = 0; rr < 4; ++rr) {
                const int row_l = wr * 64 + mi * 16 + lrow4 + rr;
                const int idx = (row_l * 128 + col_l) ^ (((row_l >> 2) & 3) << 4);
                Ct[idx] = f2bf(acc[mi][ni][rr] + bni[ni]);
            }
        }
    }
    __syncthreads();

    short* outp = isLin ? Hlinb : XLb;
    const int gcol0 = isLin ? (col0 - 256) : col0;
    const int seg = tid & 15;
    float4 sA0, sA1, sD0, sD1;
    if (!isLin) {
        sA0 = *(const float4*)(attS + col0 + seg * 8);
        sA1 = *(const float4*)(attS + col0 + seg * 8 + 4);
        sD0 = *(const float4*)(attD + col0 + seg * 8);
        sD1 = *(const float4*)(attD + col0 + seg * 8 + 4);
    }
#pragma unroll
    for (int rr8 = 0; rr8 < 8; ++rr8) {
        const int flat = tid + rr8 * 256;
        const int row = flat >> 4;
        const int sidx = (row * 128 + seg * 8) ^ (((row >> 2) & 3) << 4);
        const int grow = bm + row;
        bf16x8 vv = *(const bf16x8*)(Ct + sidx);
        if (grow < M)
            *(bf16x8*)(outp + (size_t)grow * 256 + gcol0 + seg * 8) = vv;
        if (!isLin) {
            // fused attn-prep: per-row dot with attS/attD over this block's 128 cols
            float f0 = bfs(vv[0]), f1 = bfs(vv[1]), f2 = bfs(vv[2]), f3 = bfs(vv[3]);
            float f4 = bfs(vv[4]), f5 = bfs(vv[5]), f6 = bfs(vv[6]), f7 = bfs(vv[7]);
            float sp = f0 * sA0.x + f1 * sA0.y + f2 * sA0.z + f3 * sA0.w
                     + f4 * sA1.x + f5 * sA1.y + f6 * sA1.z + f7 * sA1.w;
            float dp = f0 * sD0.x + f1 * sD0.y + f2 * sD0.z + f3 * sD0.w
                     + f4 * sD1.x + f5 * sD1.y + f6 * sD1.z + f7 * sD1.w;
            sp += __shfl_xor(sp, 1); dp += __shfl_xor(dp, 1);
            sp += __shfl_xor(sp, 2); dp += __shfl_xor(dp, 2);
            sp += __shfl_xor(sp, 4); dp += __shfl_xor(dp, 4);
            if ((seg & 7) == 0 && grow < M) {
                const int hh = (col0 >> 6) + (seg >> 3);     // heads {0,1} or {2,3}
                AS[grow * 4 + hh] = sp;
                AD[grow * 4 + hh] = dp;
            }
        }
    }
}

// ---------------- GAT aggregation: wave per node, lane per edge, 8-deep gather ----------------

__global__ __launch_bounds__(256) void gat_agg(const short* __restrict__ XLb,
                                               const float* __restrict__ AS,
                                               const float* __restrict__ AD,
                                               const int* __restrict__ rowptr,
                                               const int* __restrict__ degarr,
                                               const int* __restrict__ csr_src,
                                               const float* __restrict__ cb,
                                               const short* __restrict__ Hlinb,
                                               short* __restrict__ Hb,
                                               const float* __restrict__ cW2,
                                               const float* __restrict__ lW2,
                                               const float* __restrict__ lb2,
                                               float* __restrict__ XL2,
                                               float* __restrict__ LIN2,
                                               int n_nodes) {
    __shared__ int   sIdx[4][64];
    __shared__ float sExT[4][4][72];

    const int tid = threadIdx.x;
    const int lane = tid & 63;
    const int w = tid >> 6;
    const int n = blockIdx.x * 4 + w;
    if (n >= n_nodes) return;                  // no block-level sync in this kernel

    const int rs = rowptr[n];
    const int deg = degarr[n];
    const float4 ad4 = *(const float4*)(AD + n * 4);

    const int half = lane >> 5;
    const int l32 = lane & 31;
    const int ch0 = l32 * 8;
    const int h = l32 >> 3;

    float4 acc0 = make_float4(0.f, 0.f, 0.f, 0.f);
    float4 acc1 = make_float4(0.f, 0.f, 0.f, 0.f);
    float d0 = 0.f, d1 = 0.f, d2 = 0.f, d3 = 0.f;

    auto ACC = [&](const uint4& q, float e) {
        acc0.x += e * bflo(q.x); acc0.y += e * bfhi(q.x);
        acc0.z += e * bflo(q.y); acc0.w += e * bfhi(q.y);
        acc1.x += e * bflo(q.z); acc1.y += e * bfhi(q.z);
        acc1.z += e * bflo(q.w); acc1.w += e * bfhi(q.w);
    };

    if (deg <= 64) {
        int sv = 0;
        float c0 = -1e30f, c1 = -1e30f, c2 = -1e30f, c3 = -1e30f;
        if (lane < deg) {
            sv = csr_src[rs + lane];
            float4 a = *(const float4*)(AS + sv * 4);
            c0 = lrelu_(a.x + ad4.x); c1 = lrelu_(a.y + ad4.y);
            c2 = lrelu_(a.z + ad4.z); c3 = lrelu_(a.w + ad4.w);
        }
        float m0 = c0, m1 = c1, m2 = c2, m3 = c3;
#pragma unroll
        for (int off = 32; off > 0; off >>= 1) {
            m0 = fmaxf(m0, __shfl_xor(m0, off));
            m1 = fmaxf(m1, __shfl_xor(m1, off));
            m2 = fmaxf(m2, __shfl_xor(m2, off));
            m3 = fmaxf(m3, __shfl_xor(m3, off));
        }
        float e0 = 0.f, e1 = 0.f, e2 = 0.f, e3 = 0.f;
        if (lane < deg) {
            e0 = __expf(c0 - m0); e1 = __expf(c1 - m1);
            e2 = __expf(c2 - m2); e3 = __expf(c3 - m3);
        }
        sIdx[w][lane] = sv;
        sExT[w][0][lane] = e0; sExT[w][1][lane] = e1;
        sExT[w][2][lane] = e2; sExT[w][3][lane] = e3;
        d0 = e0; d1 = e1; d2 = e2; d3 = e3;
        __builtin_amdgcn_wave_barrier();

        const int cpad = (deg + 1) & ~1;
        int j = 0;
        for (; j + 16 <= cpad; j += 16) {      // 16 edges -> 8 independent 1KB gathers in flight
            int jj[8]; int ss[8]; float ee[8]; uint4 qq[8];
#pragma unroll
            for (int u = 0; u < 8; ++u) { jj[u] = j + 2 * u + half; ss[u] = sIdx[w][jj[u]]; ee[u] = sExT[w][h][jj[u]]; }
#pragma unroll
            for (int u = 0; u < 8; ++u) qq[u] = *(const uint4*)(XLb + (size_t)ss[u] * 256 + ch0);
#pragma unroll
            for (int u = 0; u < 8; ++u) ACC(qq[u], ee[u]);
        }
        for (; j + 8 <= cpad; j += 8) {
            int ja = j + half, jb = j + 2 + half, jc = j + 4 + half, jd = j + 6 + half;
            int sa = sIdx[w][ja], sb = sIdx[w][jb], sc = sIdx[w][jc], sd = sIdx[w][jd];
            float ea = sExT[w][h][ja], eb = sExT[w][h][jb];
            float ec = sExT[w][h][jc], ed = sExT[w][h][jd];
            uint4 qa = *(const uint4*)(XLb + (size_t)sa * 256 + ch0);
            uint4 qb = *(const uint4*)(XLb + (size_t)sb * 256 + ch0);
            uint4 qc = *(const uint4*)(XLb + (size_t)sc * 256 + ch0);
            uint4 qd = *(const uint4*)(XLb + (size_t)sd * 256 + ch0);
            ACC(qa, ea); ACC(qb, eb); ACC(qc, ec); ACC(qd, ed);
        }
        for (; j < cpad; j += 2) {
            int jj = j + half;
            int s = sIdx[w][jj];
            float e = sExT[w][h][jj];
            uint4 q = *(const uint4*)(XLb + (size_t)s * 256 + ch0);
            ACC(q, e);
        }
    } else {
        float m0 = -1e30f, m1 = -1e30f, m2 = -1e30f, m3 = -1e30f;
        for (int base = 0; base < deg; base += 64) {
            int idx = base + lane;
            if (idx < deg) {
                int s = csr_src[rs + idx];
                float4 a = *(const float4*)(AS + s * 4);
                m0 = fmaxf(m0, lrelu_(a.x + ad4.x));
                m1 = fmaxf(m1, lrelu_(a.y + ad4.y));
                m2 = fmaxf(m2, lrelu_(a.z + ad4.z));
                m3 = fmaxf(m3, lrelu_(a.w + ad4.w));
            }
        }
#pragma unroll
        for (int off = 32; off > 0; off >>= 1) {
            m0 = fmaxf(m0, __shfl_xor(m0, off));
            m1 = fmaxf(m1, __shfl_xor(m1, off));
            m2 = fmaxf(m2, __shfl_xor(m2, off));
            m3 = fmaxf(m3, __shfl_xor(m3, off));
        }
        for (int base = 0; base < deg; base += 64) {
            int cnt = deg - base; if (cnt > 64) cnt = 64;
            int idx = base + lane;
            int sv = 0;
            float e0 = 0.f, e1 = 0.f, e2 = 0.f, e3 = 0.f;
            if (idx < deg) {
                sv = csr_src[rs + idx];
                float4 a = *(const float4*)(AS + sv * 4);
                e0 = __expf(lrelu_(a.x + ad4.x) - m0);
                e1 = __expf(lrelu_(a.y + ad4.y) - m1);
                e2 = __expf(lrelu_(a.z + ad4.z) - m2);
                e3 = __expf(lrelu_(a.w + ad4.w) - m3);
            }
            sIdx[w][lane] = sv;
            sExT[w][0][lane] = e0; sExT[w][1][lane] = e1;
            sExT[w][2][lane] = e2; sExT[w][3][lane] = e3;
            d0 += e0; d1 += e1; d2 += e2; d3 += e3;
            __builtin_amdgcn_wave_barrier();
            int cpad = (cnt + 1) & ~1;
            for (int j = 0; j < cpad; j += 2) {
                int jj = j + half;
                int s = sIdx[w][jj];
                float e = sExT[w][h][jj];
                uint4 q = *(const uint4*)(XLb + (size_t)s * 256 + ch0);
                ACC(q, e);
            }
            __builtin_amdgcn_wave_barrier();
        }
    }

    acc0.x += __shfl_xor(acc0.x, 32); acc0.y += __shfl_xor(acc0.y, 32);
    acc0.z += __shfl_xor(acc0.z, 32); acc0.w += __shfl_xor(acc0.w, 32);
    acc1.x += __shfl_xor(acc1.x, 32); acc1.y += __shfl_xor(acc1.y, 32);
    acc1.z += __shfl_xor(acc1.z, 32); acc1.w += __shfl_xor(acc1.w, 32);
#pragma unroll
    for (int off = 32; off > 0; off >>= 1) {
        d0 += __shfl_xor(d0, off); d1 += __shfl_xor(d1, off);
        d2 += __shfl_xor(d2, off); d3 += __shfl_xor(d3, off);
    }
    float den = (h == 0) ? d0 : (h == 1) ? d1 : (h == 2) ? d2 : d3;
    float inv = 1.f / (den + 1e-16f);

    float v0 = 0.f, v1 = 0.f, v2 = 0.f, v3 = 0.f, v4 = 0.f, v5 = 0.f, v6 = 0.f, v7 = 0.f;
    if (lane < 32) {
        size_t o = (size_t)n * 256 + ch0;
        uint4 hq = *(const uint4*)(Hlinb + o);
        float4 cba = *(const float4*)(cb + ch0);
        float4 cbb = *(const float4*)(cb + ch0 + 4);
        v0 = elu_(acc0.x * inv + cba.x + bflo(hq.x));
        v1 = elu_(acc0.y * inv + cba.y + bfhi(hq.x));
        v2 = elu_(acc0.z * inv + cba.z + bflo(hq.y));
        v3 = elu_(acc0.w * inv + cba.w + bfhi(hq.y));
        v4 = elu_(acc1.x * inv + cbb.x + bflo(hq.z));
        v5 = elu_(acc1.y * inv + cbb.y + bfhi(hq.z));
        v6 = elu_(acc1.z * inv + cbb.z + bflo(hq.w));
        v7 = elu_(acc1.w * inv + cbb.w + bfhi(hq.w));
    }

    if (XL2 != nullptr) {
        float p0 = 0.f, p1 = 0.f, p2 = 0.f, p3 = 0.f, pl = 0.f;
        if (lane < 32) {
            const float vv[8] = {v0, v1, v2, v3, v4, v5, v6, v7};
            float4 lwa = *(const float4*)(lW2 + ch0);
            float4 lwb = *(const float4*)(lW2 + ch0 + 4);
            const float lw[8] = {lwa.x, lwa.y, lwa.z, lwa.w, lwb.x, lwb.y, lwb.z, lwb.w};
#pragma unroll
            for (int j = 0; j < 8; ++j) {
                float4 wv = *(const float4*)(cW2 + (ch0 + j) * 4);
                p0 += vv[j] * wv.x; p1 += vv[j] * wv.y;
                p2 += vv[j] * wv.z; p3 += vv[j] * wv.w;
                pl += vv[j] * lw[j];
            }
        }
#pragma unroll
        for (int off = 16; off > 0; off >>= 1) {
            p0 += __shfl_xor(p0, off); p1 += __shfl_xor(p1, off);
            p2 += __shfl_xor(p2, off); p3 += __shfl_xor(p3, off);
            pl += __shfl_xor(pl, off);
        }
        if (lane == 0) {
            *(float4*)(XL2 + n * 4) = make_float4(p0, p1, p2, p3);
            LIN2[n] = pl + lb2[0];
        }
    } else if (lane < 32) {
        size_t o = (size_t)n * 256 + ch0;
        uint4 ov;
        ov.x = (unsigned)(unsigned short)f2bf(v0) | ((unsigned)(unsigned short)f2bf(v1) << 16);
        ov.y = (unsigned)(unsigned short)f2bf(v2) | ((unsigned)(unsigned short)f2bf(v3) << 16);
        ov.z = (unsigned)(unsigned short)f2bf(v4) | ((unsigned)(unsigned short)f2bf(v5) << 16);
        ov.w = (unsigned)(unsigned short)f2bf(v6) | ((unsigned)(unsigned short)f2bf(v7) << 16);
        *(uint4*)(Hb + o) = ov;
    }
}

// ---------------- layer 2 aggregation ----------------

__global__ __launch_bounds__(256) void l2_agg(const float* __restrict__ XL2,
                                              const float* __restrict__ LIN2,
                                              const float* __restrict__ cas2,
                                              const float* __restrict__ cad2,
                                              const float* __restrict__ cb2,
                                              const int* __restrict__ rowptr,
                                              const int* __restrict__ degarr,
                                              const int* __restrict__ csr_src,
                                              float* __restrict__ out, int n_nodes) {
    int n = (blockIdx.x * blockDim.x + threadIdx.x) >> 6;
    int lane = threadIdx.x & 63;
    if (n >= n_nodes) return;
    int rs = rowptr[n], re = rs + degarr[n];
    float4 xn = *(const float4*)(XL2 + n * 4);
    float cs0 = cas2[0], cs1 = cas2[1], cs2 = cas2[2], cs3 = cas2[3];
    float cd0 = cad2[0], cd1 = cad2[1], cd2 = cad2[2], cd3 = cad2[3];
    float ad0 = xn.x * cd0, ad1 = xn.y * cd1, ad2 = xn.z * cd2, ad3 = xn.w * cd3;

    float m0 = -1e30f, m1 = -1e30f, m2 = -1e30f, m3 = -1e30f;
    for (int i = rs + lane; i < re; i += 64) {
        int s = csr_src[i];
        float4 xs = *(const float4*)(XL2 + s * 4);
        m0 = fmaxf(m0, lrelu_(xs.x * cs0 + ad0));
        m1 = fmaxf(m1, lrelu_(xs.y * cs1 + ad1));
        m2 = fmaxf(m2, lrelu_(xs.z * cs2 + ad2));
        m3 = fmaxf(m3, lrelu_(xs.w * cs3 + ad3));
    }
#pragma unroll
    for (int off = 32; off > 0; off >>= 1) {
        m0 = fmaxf(m0, __shfl_xor(m0, off));
        m1 = fmaxf(m1, __shfl_xor(m1, off));
        m2 = fmaxf(m2, __shfl_xor(m2, off));
        m3 = fmaxf(m3, __shfl_xor(m3, off));
    }

    float d0 = 0.f, d1 = 0.f, d2 = 0.f, d3 = 0.f;
    float t0 = 0.f, t1 = 0.f, t2 = 0.f, t3 = 0.f;
    for (int i = rs + lane; i < re; i += 64) {
        int s = csr_src[i];
        float4 xs = *(const float4*)(XL2 + s * 4);
        float e0 = __expf(lrelu_(xs.x * cs0 + ad0) - m0);
        float e1 = __expf(lrelu_(xs.y * cs1 + ad1) - m1);
        float e2 = __expf(lrelu_(xs.z * cs2 + ad2) - m2);
        float e3 = __expf(lrelu_(xs.w * cs3 + ad3) - m3);
        d0 += e0; d1 += e1; d2 += e2; d3 += e3;
        t0 += e0 * xs.x; t1 += e1 * xs.y; t2 += e2 * xs.z; t3 += e3 * xs.w;
    }
#pragma unroll
    for (int off = 32; off > 0; off >>= 1) {
        d0 += __shfl_xor(d0, off); d1 += __shfl_xor(d1, off);
        d2 += __shfl_xor(d2, off); d3 += __shfl_xor(d3, off);
        t0 += __shfl_xor(t0, off); t1 += __shfl_xor(t1, off);
        t2 += __shfl_xor(t2, off); t3 += __shfl_xor(t3, off);
    }
    if (lane == 0) {
        float r = 0.25f * (t0 / (d0 + 1e-16f) + t1 / (d1 + 1e-16f) +
                           t2 / (d2 + 1e-16f) + t3 / (d3 + 1e-16f));
        out[n] = r + cb2[0] + LIN2[n];
    }
}

// ---------------- launch ----------------

extern "C" void kernel_launch(void* const* d_in, const int* in_sizes, int n_in,
                              void* d_out, int out_size, void* d_ws, size_t ws_size,
                              hipStream_t stream) {
    const float* x    = (const float*)d_in[0];
    const int*   ei   = (const int*)d_in[1];
    const float* cW0  = (const float*)d_in[3];
    const float* cas0 = (const float*)d_in[4];
    const float* cad0 = (const float*)d_in[5];
    const float* cb0  = (const float*)d_in[6];
    const float* lW0  = (const float*)d_in[7];
    const float* lb0  = (const float*)d_in[8];
    const float* cW1  = (const float*)d_in[9];
    const float* cas1 = (const float*)d_in[10];
    const float* cad1 = (const float*)d_in[11];
    const float* cb1  = (const float*)d_in[12];
    const float* lW1  = (const float*)d_in[13];
    const float* lb1  = (const float*)d_in[14];
    const float* cW2  = (const float*)d_in[15];
    const float* cas2 = (const float*)d_in[16];
    const float* cad2 = (const float*)d_in[17];
    const float* cb2  = (const float*)d_in[18];
    const float* lW2  = (const float*)d_in[19];
    const float* lb2  = (const float*)d_in[20];
    float* out = (float*)d_out;

    // workspace layout (~97 MB)
    short* xb    = (short*)d_ws;                 // 6.4M bf16
    short* XLb   = xb + 6400000;                 // 12.8M bf16
    short* HAb   = XLb + 12800000;
    short* Hlinb = HAb + 12800000;               // 12.8M bf16
    short* Wt0   = Hlinb + 12800000;             // 512*128
    short* Wt1   = Wt0 + 65536;                  // 512*256
    float* AS    = (float*)(Wt1 + 131072);
    float* AD    = AS + 200000;
    float* XL2   = AD + 200000;
    float* LIN2  = XL2 + 200000;
    int* deg     = (int*)(LIN2 + NN);            // [NN]
    int* cursor  = deg + NN;                     // [NN]
    int* gcnt    = cursor + NN;                  // [4]
    int* rowptr  = gcnt + 4;                     // [NN]
    int* csr_src = rowptr + NN;                  // [ET_]

    dim3 b256(256);
    dim3 gEdges((ET_ + 255) / 256);
    dim3 gNodesWave((NN + 3) / 4);

    hipMemsetAsync(deg, 0, (2 * (size_t)NN + 4) * sizeof(int), stream);
    prep_all<<<dim3(10339), b256, 0, stream>>>(x, cW0, lW0, cW1, lW1, ei, deg, xb, Wt0, Wt1);
    alloc_scan<<<dim3((NN + 1023) / 1024), dim3(1024), 0, stream>>>(deg, rowptr, gcnt, NN);
    scatter_k<<<gEdges, b256, 0, stream>>>(ei, rowptr, cursor, csr_src);

    dim3 gemmGrid((NN + 127) / 128, 4);

    // layer 0 (GEMM computes XLb/Hlinb and AS/AD in one pass)
    gemm_bf16<<<gemmGrid, b256, 0, stream>>>(xb, Wt0, lb0, cas0, cad0, XLb, Hlinb, AS, AD, NN, 128);
    gat_agg<<<gNodesWave, b256, 0, stream>>>(XLb, AS, AD, rowptr, deg, csr_src, cb0, Hlinb,
                                             HAb, nullptr, nullptr, nullptr, nullptr, nullptr, NN);

    // layer 1 (+ fused layer-2 projections)
    gemm_bf16<<<gemmGrid, b256, 0, stream>>>(HAb, Wt1, lb1, cas1, cad1, XLb, Hlinb, AS, AD, NN, 256);
    gat_agg<<<gNodesWave, b256, 0, stream>>>(XLb, AS, AD, rowptr, deg, csr_src, cb1, Hlinb,
                                             nullptr, cW2, lW2, lb2, XL2, LIN2, NN);

    // layer 2 aggregation
    l2_agg<<<gNodesWave, b256, 0, stream>>>(XL2, LIN2, cas2, cad2, cb2, rowptr, deg, csr_src, out, NN);
}

// Round 9
// 450.339 us; speedup vs baseline: 1.0363x; 1.0363x over previous
//
#include <hip/hip_runtime.h>
#include <cstddef>
#include <cstdint>

#define NN 50000
#define EE 800000
#define ET_ (EE + NN)

typedef __attribute__((ext_vector_type(8))) short bf16x8;
typedef __attribute__((ext_vector_type(4))) float f32x4;

__device__ __forceinline__ float lrelu_(float x) { return x > 0.f ? x : 0.2f * x; }
__device__ __forceinline__ float elu_(float x)   { return x > 0.f ? x : (__expf(x) - 1.f); }
__device__ __forceinline__ short f2bf(float f) {
    unsigned u = __float_as_uint(f);
    unsigned r = (u + 0x7fffu + ((u >> 16) & 1u)) >> 16;
    return (short)r;
}
__device__ __forceinline__ float bflo(unsigned u) { return __uint_as_float(u << 16); }
__device__ __forceinline__ float bfhi(unsigned u) { return __uint_as_float(u & 0xffff0000u); }
__device__ __forceinline__ float bfs(short s) { return __uint_as_float(((unsigned)(unsigned short)s) << 16); }

#define GL16(gp, lp) __builtin_amdgcn_global_load_lds( \
    (const __attribute__((address_space(1))) unsigned int*)(gp), \
    (__attribute__((address_space(3))) unsigned int*)(lp), 16, 0, 0)

// ---------------- fused prep: x->bf16, pack Wt0/Wt1, degree histogram ----------------

__global__ __launch_bounds__(256) void prep_all(const float* __restrict__ x,
                                                const float* __restrict__ cW0, const float* __restrict__ lW0,
                                                const float* __restrict__ cW1, const float* __restrict__ lW1,
                                                const int* __restrict__ ei, int* __restrict__ deg,
                                                short* __restrict__ xb, short* __restrict__ Wt0,
                                                short* __restrict__ Wt1) {
    int i = blockIdx.x * 256 + threadIdx.x;
    if (i < 1600000) {
        float4 v = *(const float4*)(x + (size_t)i * 4);
        short4 o;
        o.x = f2bf(v.x); o.y = f2bf(v.y); o.z = f2bf(v.z); o.w = f2bf(v.w);
        *(short4*)(xb + (size_t)i * 4) = o;
        return;
    }
    i -= 1600000;
    if (i < 512 * 128) {
        int n = i >> 7, k = i & 127;
        float v = (n < 256) ? cW0[k * 256 + n] : lW0[k * 256 + (n - 256)];
        Wt0[i] = f2bf(v);
        return;
    }
    i -= 512 * 128;
    if (i < 512 * 256) {
        int n = i >> 8, k = i & 255;
        float v = (n < 256) ? cW1[k * 256 + n] : lW1[k * 256 + (n - 256)];
        Wt1[i] = f2bf(v);
        return;
    }
    i -= 512 * 256;
    if (i < ET_) {
        int d = (i < EE) ? ei[EE + i] : (i - EE);
        atomicAdd(&deg[d], 1);
    }
}

// ---------------- CSR build ----------------

__global__ __launch_bounds__(1024) void alloc_scan(const int* __restrict__ deg, int* __restrict__ rowptr,
                                                   int* __restrict__ gcnt, int n) {
    __shared__ int s[1024];
    __shared__ int basesh;
    int tid = threadIdx.x;
    int gid = blockIdx.x * 1024 + tid;
    int v = (gid < n) ? deg[gid] : 0;
    s[tid] = v;
    __syncthreads();
    for (int off = 1; off < 1024; off <<= 1) {
        int t = (tid >= off) ? s[tid - off] : 0;
        __syncthreads();
        s[tid] += t;
        __syncthreads();
    }
    if (tid == 1023) basesh = atomicAdd(gcnt, s[1023]);
    __syncthreads();
    if (gid < n) rowptr[gid] = basesh + s[tid] - v;
}

__global__ __launch_bounds__(256) void scatter_k(const int* __restrict__ ei,
                                                 const int* __restrict__ rowptr,
                                                 int* __restrict__ cursor,
                                                 int* __restrict__ csr_src) {
    int e = blockIdx.x * blockDim.x + threadIdx.x;
    if (e >= ET_) return;
    int s, d;
    if (e < EE) { s = ei[e]; d = ei[EE + e]; } else { s = e - EE; d = e - EE; }
    int pos = atomicAdd(&cursor[d], 1);
    csr_src[rowptr[d] + pos] = s;
}

// ---------------- bf16 MFMA GEMM, dbuf + LDS epilogue + fused attn-prep ----------------

__global__ __launch_bounds__(256) void gemm_bf16(const short* __restrict__ A,
                                                 const short* __restrict__ Wt,
                                                 const float* __restrict__ biasLin,
                                                 const float* __restrict__ attS,
                                                 const float* __restrict__ attD,
                                                 short* __restrict__ XLb,
                                                 short* __restrict__ Hlinb,
                                                 float* __restrict__ AS,
                                                 float* __restrict__ AD,
                                                 int M, int K) {
    __shared__ short smem[4][128 * 32];     // As0|As1|Bs0|Bs1, aliased as C-tile after loop
    const int tid = threadIdx.x;
    const int lane = tid & 63;
    const int wid = tid >> 6;
    const int bm = blockIdx.x * 128;
    const int col0 = blockIdx.y * 128;
    const int wr = wid >> 1, wc = wid & 1;

    f32x4 acc[4][4];
#pragma unroll
    for (int i = 0; i < 4; ++i)
#pragma unroll
        for (int j = 0; j < 4; ++j) acc[i][j] = (f32x4){0.f, 0.f, 0.f, 0.f};

    const int lrow = lane & 15, lk = lane >> 4;

    auto stage = [&](int b, int kk) {
#pragma unroll
        for (int it = 0; it < 2; ++it) {
            const int flat = tid + it * 256;
            const int row = flat >> 2, slot = flat & 3;
            const int ss = slot ^ (row & 3);
            int ar = bm + row; ar = (ar < M) ? ar : (M - 1);
            GL16(A + (size_t)ar * K + kk + ss * 8, &smem[b][flat * 8]);
            GL16(Wt + (size_t)(col0 + row) * K + kk + ss * 8, &smem[2 + b][flat * 8]);
        }
    };

    stage(0, 0);
    int cur = 0;
    for (int k0 = 0; k0 < K; k0 += 32) {
        __syncthreads();
        if (k0 + 32 < K) stage(cur ^ 1, k0 + 32);
        bf16x8 af[4], bfr[4];
#pragma unroll
        for (int mi = 0; mi < 4; ++mi) {
            const int r = wr * 64 + mi * 16 + lrow;
            af[mi] = *(const bf16x8*)(&smem[cur][(r * 4 + (lk ^ (r & 3))) * 8]);
        }
#pragma unroll
        for (int ni = 0; ni < 4; ++ni) {
            const int c = wc * 64 + ni * 16 + lrow;
            bfr[ni] = *(const bf16x8*)(&smem[2 + cur][(c * 4 + (lk ^ (c & 3))) * 8]);
        }
#pragma unroll
        for (int mi = 0; mi < 4; ++mi)
#pragma unroll
            for (int ni = 0; ni < 4; ++ni)
                acc[mi][ni] = __builtin_amdgcn_mfma_f32_16x16x32_bf16(af[mi], bfr[ni], acc[mi][ni], 0, 0, 0);
        cur ^= 1;
    }

    __syncthreads();                        // reuse smem as C-tile [128][128] bf16, XOR-swizzled
    short* Ct = &smem[0][0];
    const bool isLin = (col0 >= 256);
    float bni[4] = {0.f, 0.f, 0.f, 0.f};
    if (isLin) {
#pragma unroll
        for (int ni = 0; ni < 4; ++ni)
            bni[ni] = biasLin[col0 - 256 + wc * 64 + ni * 16 + lrow];
    }
    const int lrow4 = lk * 4;
#pragma unroll
    for (int mi = 0; mi < 4; ++mi) {
#pragma unroll
        for (int ni = 0; ni < 4; ++ni) {
            const int col_l = wc * 64 + ni * 16 + lrow;
#pragma unroll
            for (int rr = 0; rr < 4; ++rr) {
                const int row_l = wr * 64 + mi * 16 + lrow4 + rr;
                const int idx = (row_l * 128 + col_l) ^ (((row_l >> 2) & 3) << 4);
                Ct[idx] = f2bf(acc[mi][ni][rr] + bni[ni]);
            }
        }
    }
    __syncthreads();

    short* outp = isLin ? Hlinb : XLb;
    const int gcol0 = isLin ? (col0 - 256) : col0;
    const int seg = tid & 15;
    float4 sA0, sA1, sD0, sD1;
    if (!isLin) {
        sA0 = *(const float4*)(attS + col0 + seg * 8);
        sA1 = *(const float4*)(attS + col0 + seg * 8 + 4);
        sD0 = *(const float4*)(attD + col0 + seg * 8);
        sD1 = *(const float4*)(attD + col0 + seg * 8 + 4);
    }
#pragma unroll
    for (int rr8 = 0; rr8 < 8; ++rr8) {
        const int flat = tid + rr8 * 256;
        const int row = flat >> 4;
        const int sidx = (row * 128 + seg * 8) ^ (((row >> 2) & 3) << 4);
        const int grow = bm + row;
        bf16x8 vv = *(const bf16x8*)(Ct + sidx);
        if (grow < M)
            *(bf16x8*)(outp + (size_t)grow * 256 + gcol0 + seg * 8) = vv;
        if (!isLin) {
            float f0 = bfs(vv[0]), f1 = bfs(vv[1]), f2 = bfs(vv[2]), f3 = bfs(vv[3]);
            float f4 = bfs(vv[4]), f5 = bfs(vv[5]), f6 = bfs(vv[6]), f7 = bfs(vv[7]);
            float sp = f0 * sA0.x + f1 * sA0.y + f2 * sA0.z + f3 * sA0.w
                     + f4 * sA1.x + f5 * sA1.y + f6 * sA1.z + f7 * sA1.w;
            float dp = f0 * sD0.x + f1 * sD0.y + f2 * sD0.z + f3 * sD0.w
                     + f4 * sD1.x + f5 * sD1.y + f6 * sD1.z + f7 * sD1.w;
            sp += __shfl_xor(sp, 1); dp += __shfl_xor(dp, 1);
            sp += __shfl_xor(sp, 2); dp += __shfl_xor(dp, 2);
            sp += __shfl_xor(sp, 4); dp += __shfl_xor(dp, 4);
            if ((seg & 7) == 0 && grow < M) {
                const int hh = (col0 >> 6) + (seg >> 3);
                AS[grow * 4 + hh] = sp;
                AD[grow * 4 + hh] = dp;
            }
        }
    }
}

// ---------------- shared GAT-aggregation core (wave per node, simple 2-edge gather) ----------------

__device__ __forceinline__ void agg_core(const short* __restrict__ XLb,
                                         const float* __restrict__ AS,
                                         const float4 ad4,
                                         int rs, int deg,
                                         const int* __restrict__ csr_src,
                                         int w, int lane,
                                         int (*sIdx)[64], float (*sExT)[4][72],
                                         float4& acc0, float4& acc1, float& denOut,
                                         int half, int l32, int ch0, int h) {
    float d0 = 0.f, d1 = 0.f, d2 = 0.f, d3 = 0.f;

    if (deg <= 64) {
        int sv = 0;
        float c0 = -1e30f, c1 = -1e30f, c2 = -1e30f, c3 = -1e30f;
        if (lane < deg) {
            sv = csr_src[rs + lane];
            float4 a = *(const float4*)(AS + sv * 4);
            c0 = lrelu_(a.x + ad4.x); c1 = lrelu_(a.y + ad4.y);
            c2 = lrelu_(a.z + ad4.z); c3 = lrelu_(a.w + ad4.w);
        }
        float m0 = c0, m1 = c1, m2 = c2, m3 = c3;
#pragma unroll
        for (int off = 32; off > 0; off >>= 1) {
            m0 = fmaxf(m0, __shfl_xor(m0, off));
            m1 = fmaxf(m1, __shfl_xor(m1, off));
            m2 = fmaxf(m2, __shfl_xor(m2, off));
            m3 = fmaxf(m3, __shfl_xor(m3, off));
        }
        float e0 = 0.f, e1 = 0.f, e2 = 0.f, e3 = 0.f;
        if (lane < deg) {
            e0 = __expf(c0 - m0); e1 = __expf(c1 - m1);
            e2 = __expf(c2 - m2); e3 = __expf(c3 - m3);
        }
        sIdx[w][lane] = sv;
        sExT[w][0][lane] = e0; sExT[w][1][lane] = e1;
        sExT[w][2][lane] = e2; sExT[w][3][lane] = e3;
        d0 = e0; d1 = e1; d2 = e2; d3 = e3;
        __builtin_amdgcn_wave_barrier();

        const int cpad = (deg + 1) & ~1;
        for (int j = 0; j < cpad; j += 2) {
            int jj = j + half;
            int s = sIdx[w][jj];
            float e = sExT[w][h][jj];
            const uint4 q = *(const uint4*)(XLb + (size_t)s * 256 + ch0);
            acc0.x += e * bflo(q.x); acc0.y += e * bfhi(q.x);
            acc0.z += e * bflo(q.y); acc0.w += e * bfhi(q.y);
            acc1.x += e * bflo(q.z); acc1.y += e * bfhi(q.z);
            acc1.z += e * bflo(q.w); acc1.w += e * bfhi(q.w);
        }
    } else {
        float m0 = -1e30f, m1 = -1e30f, m2 = -1e30f, m3 = -1e30f;
        for (int base = 0; base < deg; base += 64) {
            int idx = base + lane;
            if (idx < deg) {
                int s = csr_src[rs + idx];
                float4 a = *(const float4*)(AS + s * 4);
                m0 = fmaxf(m0, lrelu_(a.x + ad4.x));
                m1 = fmaxf(m1, lrelu_(a.y + ad4.y));
                m2 = fmaxf(m2, lrelu_(a.z + ad4.z));
                m3 = fmaxf(m3, lrelu_(a.w + ad4.w));
            }
        }
#pragma unroll
        for (int off = 32; off > 0; off >>= 1) {
            m0 = fmaxf(m0, __shfl_xor(m0, off));
            m1 = fmaxf(m1, __shfl_xor(m1, off));
            m2 = fmaxf(m2, __shfl_xor(m2, off));
            m3 = fmaxf(m3, __shfl_xor(m3, off));
        }
        for (int base = 0; base < deg; base += 64) {
            int cnt = deg - base; if (cnt > 64) cnt = 64;
            int idx = base + lane;
            int sv = 0;
            float e0 = 0.f, e1 = 0.f, e2 = 0.f, e3 = 0.f;
            if (idx < deg) {
                sv = csr_src[rs + idx];
                float4 a = *(const float4*)(AS + sv * 4);
                e0 = __expf(lrelu_(a.x + ad4.x) - m0);
                e1 = __expf(lrelu_(a.y + ad4.y) - m1);
                e2 = __expf(lrelu_(a.z + ad4.z) - m2);
                e3 = __expf(lrelu_(a.w + ad4.w) - m3);
            }
            sIdx[w][lane] = sv;
            sExT[w][0][lane] = e0; sExT[w][1][lane] = e1;
            sExT[w][2][lane] = e2; sExT[w][3][lane] = e3;
            d0 += e0; d1 += e1; d2 += e2; d3 += e3;
            __builtin_amdgcn_wave_barrier();
            int cpad = (cnt + 1) & ~1;
            for (int j = 0; j < cpad; j += 2) {
                int jj = j + half;
                int s = sIdx[w][jj];
                float e = sExT[w][h][jj];
                const uint4 q = *(const uint4*)(XLb + (size_t)s * 256 + ch0);
                acc0.x += e * bflo(q.x); acc0.y += e * bfhi(q.x);
                acc0.z += e * bflo(q.y); acc0.w += e * bfhi(q.y);
                acc1.x += e * bflo(q.z); acc1.y += e * bfhi(q.z);
                acc1.z += e * bflo(q.w); acc1.w += e * bfhi(q.w);
            }
            __builtin_amdgcn_wave_barrier();
        }
    }

    acc0.x += __shfl_xor(acc0.x, 32); acc0.y += __shfl_xor(acc0.y, 32);
    acc0.z += __shfl_xor(acc0.z, 32); acc0.w += __shfl_xor(acc0.w, 32);
    acc1.x += __shfl_xor(acc1.x, 32); acc1.y += __shfl_xor(acc1.y, 32);
    acc1.z += __shfl_xor(acc1.z, 32); acc1.w += __shfl_xor(acc1.w, 32);
#pragma unroll
    for (int off = 32; off > 0; off >>= 1) {
        d0 += __shfl_xor(d0, off); d1 += __shfl_xor(d1, off);
        d2 += __shfl_xor(d2, off); d3 += __shfl_xor(d3, off);
    }
    denOut = (h == 0) ? d0 : (h == 1) ? d1 : (h == 2) ? d2 : d3;
}

// ---------------- layer-0 aggregation: write Hb (bf16) ----------------

__global__ __launch_bounds__(256, 8) void gat_agg0(const short* __restrict__ XLb,
                                                   const float* __restrict__ AS,
                                                   const float* __restrict__ AD,
                                                   const int* __restrict__ rowptr,
                                                   const int* __restrict__ degarr,
                                                   const int* __restrict__ csr_src,
                                                   const float* __restrict__ cb,
                                                   const short* __restrict__ Hlinb,
                                                   short* __restrict__ Hb, int n_nodes) {
    __shared__ int   sIdx[4][64];
    __shared__ float sExT[4][4][72];
    const int tid = threadIdx.x;
    const int lane = tid & 63;
    const int w = tid >> 6;
    const int n = blockIdx.x * 4 + w;
    if (n >= n_nodes) return;

    const int rs = rowptr[n];
    const int deg = degarr[n];
    const float4 ad4 = *(const float4*)(AD + n * 4);
    const int half = lane >> 5, l32 = lane & 31, ch0 = l32 * 8, h = l32 >> 3;

    float4 acc0 = make_float4(0.f, 0.f, 0.f, 0.f);
    float4 acc1 = make_float4(0.f, 0.f, 0.f, 0.f);
    float den;
    agg_core(XLb, AS, ad4, rs, deg, csr_src, w, lane, sIdx, sExT, acc0, acc1, den,
             half, l32, ch0, h);
    float inv = 1.f / (den + 1e-16f);

    if (lane < 32) {
        size_t o = (size_t)n * 256 + ch0;
        uint4 hq = *(const uint4*)(Hlinb + o);
        float4 cba = *(const float4*)(cb + ch0);
        float4 cbb = *(const float4*)(cb + ch0 + 4);
        float v0 = elu_(acc0.x * inv + cba.x + bflo(hq.x));
        float v1 = elu_(acc0.y * inv + cba.y + bfhi(hq.x));
        float v2 = elu_(acc0.z * inv + cba.z + bflo(hq.y));
        float v3 = elu_(acc0.w * inv + cba.w + bfhi(hq.y));
        float v4 = elu_(acc1.x * inv + cbb.x + bflo(hq.z));
        float v5 = elu_(acc1.y * inv + cbb.y + bfhi(hq.z));
        float v6 = elu_(acc1.z * inv + cbb.z + bflo(hq.w));
        float v7 = elu_(acc1.w * inv + cbb.w + bfhi(hq.w));
        uint4 ov;
        ov.x = (unsigned)(unsigned short)f2bf(v0) | ((unsigned)(unsigned short)f2bf(v1) << 16);
        ov.y = (unsigned)(unsigned short)f2bf(v2) | ((unsigned)(unsigned short)f2bf(v3) << 16);
        ov.z = (unsigned)(unsigned short)f2bf(v4) | ((unsigned)(unsigned short)f2bf(v5) << 16);
        ov.w = (unsigned)(unsigned short)f2bf(v6) | ((unsigned)(unsigned short)f2bf(v7) << 16);
        *(uint4*)(Hb + o) = ov;
    }
}

// ---------------- layer-1 aggregation: fused layer-2 projections ----------------

__global__ __launch_bounds__(256, 8) void gat_agg1(const short* __restrict__ XLb,
                                                   const float* __restrict__ AS,
                                                   const float* __restrict__ AD,
                                                   const int* __restrict__ rowptr,
                                                   const int* __restrict__ degarr,
                                                   const int* __restrict__ csr_src,
                                                   const float* __restrict__ cb,
                                                   const short* __restrict__ Hlinb,
                                                   const float* __restrict__ cW2,
                                                   const float* __restrict__ lW2,
                                                   const float* __restrict__ lb2,
                                                   float* __restrict__ XL2,
                                                   float* __restrict__ LIN2, int n_nodes) {
    __shared__ int   sIdx[4][64];
    __shared__ float sExT[4][4][72];
    const int tid = threadIdx.x;
    const int lane = tid & 63;
    const int w = tid >> 6;
    const int n = blockIdx.x * 4 + w;
    if (n >= n_nodes) return;

    const int rs = rowptr[n];
    const int deg = degarr[n];
    const float4 ad4 = *(const float4*)(AD + n * 4);
    const int half = lane >> 5, l32 = lane & 31, ch0 = l32 * 8, h = l32 >> 3;

    float4 acc0 = make_float4(0.f, 0.f, 0.f, 0.f);
    float4 acc1 = make_float4(0.f, 0.f, 0.f, 0.f);
    float den;
    agg_core(XLb, AS, ad4, rs, deg, csr_src, w, lane, sIdx, sExT, acc0, acc1, den,
             half, l32, ch0, h);
    float inv = 1.f / (den + 1e-16f);

    float p0 = 0.f, p1 = 0.f, p2 = 0.f, p3 = 0.f, pl = 0.f;
    if (lane < 32) {
        size_t o = (size_t)n * 256 + ch0;
        uint4 hq = *(const uint4*)(Hlinb + o);
        float4 cba = *(const float4*)(cb + ch0);
        float4 cbb = *(const float4*)(cb + ch0 + 4);
        float vv[8];
        vv[0] = elu_(acc0.x * inv + cba.x + bflo(hq.x));
        vv[1] = elu_(acc0.y * inv + cba.y + bfhi(hq.x));
        vv[2] = elu_(acc0.z * inv + cba.z + bflo(hq.y));
        vv[3] = elu_(acc0.w * inv + cba.w + bfhi(hq.y));
        vv[4] = elu_(acc1.x * inv + cbb.x + bflo(hq.z));
        vv[5] = elu_(acc1.y * inv + cbb.y + bfhi(hq.z));
        vv[6] = elu_(acc1.z * inv + cbb.z + bflo(hq.w));
        vv[7] = elu_(acc1.w * inv + cbb.w + bfhi(hq.w));
        float4 lwa = *(const float4*)(lW2 + ch0);
        float4 lwb = *(const float4*)(lW2 + ch0 + 4);
        const float lw[8] = {lwa.x, lwa.y, lwa.z, lwa.w, lwb.x, lwb.y, lwb.z, lwb.w};
#pragma unroll
        for (int j = 0; j < 8; ++j) {
            float4 wv = *(const float4*)(cW2 + (ch0 + j) * 4);
            p0 += vv[j] * wv.x; p1 += vv[j] * wv.y;
            p2 += vv[j] * wv.z; p3 += vv[j] * wv.w;
            pl += vv[j] * lw[j];
        }
    }
#pragma unroll
    for (int off = 16; off > 0; off >>= 1) {
        p0 += __shfl_xor(p0, off); p1 += __shfl_xor(p1, off);
        p2 += __shfl_xor(p2, off); p3 += __shfl_xor(p3, off);
        pl += __shfl_xor(pl, off);
    }
    if (lane == 0) {
        *(float4*)(XL2 + n * 4) = make_float4(p0, p1, p2, p3);
        LIN2[n] = pl + lb2[0];
    }
}

// ---------------- layer 2 aggregation (deg<=64 single-pass fast path) ----------------

__global__ __launch_bounds__(256, 8) void l2_agg(const float* __restrict__ XL2,
                                                 const float* __restrict__ LIN2,
                                                 const float* __restrict__ cas2,
                                                 const float* __restrict__ cad2,
                                                 const float* __restrict__ cb2,
                                                 const int* __restrict__ rowptr,
                                                 const int* __restrict__ degarr,
                                                 const int* __restrict__ csr_src,
                                                 float* __restrict__ out, int n_nodes) {
    int n = (blockIdx.x * blockDim.x + threadIdx.x) >> 6;
    int lane = threadIdx.x & 63;
    if (n >= n_nodes) return;
    int rs = rowptr[n];
    int deg = degarr[n];
    float4 xn = *(const float4*)(XL2 + n * 4);
    float cs0 = cas2[0], cs1 = cas2[1], cs2 = cas2[2], cs3 = cas2[3];
    float cd0 = cad2[0], cd1 = cad2[1], cd2 = cad2[2], cd3 = cad2[3];
    float ad0 = xn.x * cd0, ad1 = xn.y * cd1, ad2 = xn.z * cd2, ad3 = xn.w * cd3;

    float d0 = 0.f, d1 = 0.f, d2 = 0.f, d3 = 0.f;
    float t0 = 0.f, t1 = 0.f, t2 = 0.f, t3 = 0.f;

    if (deg <= 64) {
        float4 xs = make_float4(0.f, 0.f, 0.f, 0.f);
        float c0 = -1e30f, c1 = -1e30f, c2 = -1e30f, c3 = -1e30f;
        if (lane < deg) {
            int s = csr_src[rs + lane];
            xs = *(const float4*)(XL2 + s * 4);
            c0 = lrelu_(xs.x * cs0 + ad0); c1 = lrelu_(xs.y * cs1 + ad1);
            c2 = lrelu_(xs.z * cs2 + ad2); c3 = lrelu_(xs.w * cs3 + ad3);
        }
        float m0 = c0, m1 = c1, m2 = c2, m3 = c3;
#pragma unroll
        for (int off = 32; off > 0; off >>= 1) {
            m0 = fmaxf(m0, __shfl_xor(m0, off));
            m1 = fmaxf(m1, __shfl_xor(m1, off));
            m2 = fmaxf(m2, __shfl_xor(m2, off));
            m3 = fmaxf(m3, __shfl_xor(m3, off));
        }
        if (lane < deg) {
            float e0 = __expf(c0 - m0), e1 = __expf(c1 - m1);
            float e2 = __expf(c2 - m2), e3 = __expf(c3 - m3);
            d0 = e0; d1 = e1; d2 = e2; d3 = e3;
            t0 = e0 * xs.x; t1 = e1 * xs.y; t2 = e2 * xs.z; t3 = e3 * xs.w;
        }
    } else {
        int re = rs + deg;
        float m0 = -1e30f, m1 = -1e30f, m2 = -1e30f, m3 = -1e30f;
        for (int i = rs + lane; i < re; i += 64) {
            int s = csr_src[i];
            float4 xs = *(const float4*)(XL2 + s * 4);
            m0 = fmaxf(m0, lrelu_(xs.x * cs0 + ad0));
            m1 = fmaxf(m1, lrelu_(xs.y * cs1 + ad1));
            m2 = fmaxf(m2, lrelu_(xs.z * cs2 + ad2));
            m3 = fmaxf(m3, lrelu_(xs.w * cs3 + ad3));
        }
#pragma unroll
        for (int off = 32; off > 0; off >>= 1) {
            m0 = fmaxf(m0, __shfl_xor(m0, off));
            m1 = fmaxf(m1, __shfl_xor(m1, off));
            m2 = fmaxf(m2, __shfl_xor(m2, off));
            m3 = fmaxf(m3, __shfl_xor(m3, off));
        }
        for (int i = rs + lane; i < re; i += 64) {
            int s = csr_src[i];
            float4 xs = *(const float4*)(XL2 + s * 4);
            float e0 = __expf(lrelu_(xs.x * cs0 + ad0) - m0);
            float e1 = __expf(lrelu_(xs.y * cs1 + ad1) - m1);
            float e2 = __expf(lrelu_(xs.z * cs2 + ad2) - m2);
            float e3 = __expf(lrelu_(xs.w * cs3 + ad3) - m3);
            d0 += e0; d1 += e1; d2 += e2; d3 += e3;
            t0 += e0 * xs.x; t1 += e1 * xs.y; t2 += e2 * xs.z; t3 += e3 * xs.w;
        }
    }
#pragma unroll
    for (int off = 32; off > 0; off >>= 1) {
        d0 += __shfl_xor(d0, off); d1 += __shfl_xor(d1, off);
        d2 += __shfl_xor(d2, off); d3 += __shfl_xor(d3, off);
        t0 += __shfl_xor(t0, off); t1 += __shfl_xor(t1, off);
        t2 += __shfl_xor(t2, off); t3 += __shfl_xor(t3, off);
    }
    if (lane == 0) {
        float r = 0.25f * (t0 / (d0 + 1e-16f) + t1 / (d1 + 1e-16f) +
                           t2 / (d2 + 1e-16f) + t3 / (d3 + 1e-16f));
        out[n] = r + cb2[0] + LIN2[n];
    }
}

// ---------------- launch ----------------

extern "C" void kernel_launch(void* const* d_in, const int* in_sizes, int n_in,
                              void* d_out, int out_size, void* d_ws, size_t ws_size,
                              hipStream_t stream) {
    const float* x    = (const float*)d_in[0];
    const int*   ei   = (const int*)d_in[1];
    const float* cW0  = (const float*)d_in[3];
    const float* cas0 = (const float*)d_in[4];
    const float* cad0 = (const float*)d_in[5];
    const float* cb0  = (const float*)d_in[6];
    const float* lW0  = (const float*)d_in[7];
    const float* lb0  = (const float*)d_in[8];
    const float* cW1  = (const float*)d_in[9];
    const float* cas1 = (const float*)d_in[10];
    const float* cad1 = (const float*)d_in[11];
    const float* cb1  = (const float*)d_in[12];
    const float* lW1  = (const float*)d_in[13];
    const float* lb1  = (const float*)d_in[14];
    const float* cW2  = (const float*)d_in[15];
    const float* cas2 = (const float*)d_in[16];
    const float* cad2 = (const float*)d_in[17];
    const float* cb2  = (const float*)d_in[18];
    const float* lW2  = (const float*)d_in[19];
    const float* lb2  = (const float*)d_in[20];
    float* out = (float*)d_out;

    // workspace layout (~97 MB)
    short* xb    = (short*)d_ws;                 // 6.4M bf16
    short* XLb   = xb + 6400000;                 // 12.8M bf16
    short* HAb   = XLb + 12800000;
    short* Hlinb = HAb + 12800000;               // 12.8M bf16
    short* Wt0   = Hlinb + 12800000;             // 512*128
    short* Wt1   = Wt0 + 65536;                  // 512*256
    float* AS    = (float*)(Wt1 + 131072);
    float* AD    = AS + 200000;
    float* XL2   = AD + 200000;
    float* LIN2  = XL2 + 200000;
    int* deg     = (int*)(LIN2 + NN);            // [NN]
    int* cursor  = deg + NN;                     // [NN]
    int* gcnt    = cursor + NN;                  // [4]
    int* rowptr  = gcnt + 4;                     // [NN]
    int* csr_src = rowptr + NN;                  // [ET_]

    dim3 b256(256);
    dim3 gEdges((ET_ + 255) / 256);
    dim3 gNodesWave((NN + 3) / 4);

    hipMemsetAsync(deg, 0, (2 * (size_t)NN + 4) * sizeof(int), stream);
    prep_all<<<dim3(10339), b256, 0, stream>>>(x, cW0, lW0, cW1, lW1, ei, deg, xb, Wt0, Wt1);
    alloc_scan<<<dim3((NN + 1023) / 1024), dim3(1024), 0, stream>>>(deg, rowptr, gcnt, NN);
    scatter_k<<<gEdges, b256, 0, stream>>>(ei, rowptr, cursor, csr_src);

    dim3 gemmGrid((NN + 127) / 128, 4);

    // layer 0 (GEMM computes XLb/Hlinb and AS/AD in one pass)
    gemm_bf16<<<gemmGrid, b256, 0, stream>>>(xb, Wt0, lb0, cas0, cad0, XLb, Hlinb, AS, AD, NN, 128);
    gat_agg0<<<gNodesWave, b256, 0, stream>>>(XLb, AS, AD, rowptr, deg, csr_src, cb0, Hlinb, HAb, NN);

    // layer 1 (+ fused layer-2 projections)
    gemm_bf16<<<gemmGrid, b256, 0, stream>>>(HAb, Wt1, lb1, cas1, cad1, XLb, Hlinb, AS, AD, NN, 256);
    gat_agg1<<<gNodesWave, b256, 0, stream>>>(XLb, AS, AD, rowptr, deg, csr_src, cb1, Hlinb,
                                              cW2, lW2, lb2, XL2, LIN2, NN);

    // layer 2 aggregation
    l2_agg<<<gNodesWave, b256, 0, stream>>>(XL2, LIN2, cas2, cad2, cb2, rowptr, deg, csr_src, out, NN);
}

// Round 10
// 445.865 us; speedup vs baseline: 1.0467x; 1.0100x over previous
//
#include <hip/hip_runtime.h>
#include <cstddef>
#include <cstdint>

#define NN 50000
#define EE 800000
#define ET_ (EE + NN)

typedef __attribute__((ext_vector_type(8))) short bf16x8;
typedef __attribute__((ext_vector_type(4))) float f32x4;

__device__ __forceinline__ float lrelu_(float x) { return x > 0.f ? x : 0.2f * x; }
__device__ __forceinline__ float elu_(float x)   { return x > 0.f ? x : (__expf(x) - 1.f); }
__device__ __forceinline__ short f2bf(float f) {
    unsigned u = __float_as_uint(f);
    unsigned r = (u + 0x7fffu + ((u >> 16) & 1u)) >> 16;
    return (short)r;
}
__device__ __forceinline__ float bflo(unsigned u) { return __uint_as_float(u << 16); }
__device__ __forceinline__ float bfhi(unsigned u) { return __uint_as_float(u & 0xffff0000u); }
__device__ __forceinline__ float bfs(short s) { return __uint_as_float(((unsigned)(unsigned short)s) << 16); }

#define GL16(gp, lp) __builtin_amdgcn_global_load_lds( \
    (const __attribute__((address_space(1))) unsigned int*)(gp), \
    (__attribute__((address_space(3))) unsigned int*)(lp), 16, 0, 0)

// ---------------- fused prep: x->bf16, pack Wt0/Wt1, degree histogram ----------------

__global__ __launch_bounds__(256) void prep_all(const float* __restrict__ x,
                                                const float* __restrict__ cW0, const float* __restrict__ lW0,
                                                const float* __restrict__ cW1, const float* __restrict__ lW1,
                                                const int* __restrict__ ei, int* __restrict__ deg,
                                                short* __restrict__ xb, short* __restrict__ Wt0,
                                                short* __restrict__ Wt1) {
    int i = blockIdx.x * 256 + threadIdx.x;
    if (i < 1600000) {
        float4 v = *(const float4*)(x + (size_t)i * 4);
        short4 o;
        o.x = f2bf(v.x); o.y = f2bf(v.y); o.z = f2bf(v.z); o.w = f2bf(v.w);
        *(short4*)(xb + (size_t)i * 4) = o;
        return;
    }
    i -= 1600000;
    if (i < 512 * 128) {
        int n = i >> 7, k = i & 127;
        float v = (n < 256) ? cW0[k * 256 + n] : lW0[k * 256 + (n - 256)];
        Wt0[i] = f2bf(v);
        return;
    }
    i -= 512 * 128;
    if (i < 512 * 256) {
        int n = i >> 8, k = i & 255;
        float v = (n < 256) ? cW1[k * 256 + n] : lW1[k * 256 + (n - 256)];
        Wt1[i] = f2bf(v);
        return;
    }
    i -= 512 * 256;
    if (i < ET_) {
        int d = (i < EE) ? ei[EE + i] : (i - EE);
        atomicAdd(&deg[d], 1);
    }
}

// ---------------- CSR build ----------------

__global__ __launch_bounds__(1024) void alloc_scan(const int* __restrict__ deg, int* __restrict__ rowptr,
                                                   int* __restrict__ gcnt, int n) {
    __shared__ int s[1024];
    __shared__ int basesh;
    int tid = threadIdx.x;
    int gid = blockIdx.x * 1024 + tid;
    int v = (gid < n) ? deg[gid] : 0;
    s[tid] = v;
    __syncthreads();
    for (int off = 1; off < 1024; off <<= 1) {
        int t = (tid >= off) ? s[tid - off] : 0;
        __syncthreads();
        s[tid] += t;
        __syncthreads();
    }
    if (tid == 1023) basesh = atomicAdd(gcnt, s[1023]);
    __syncthreads();
    if (gid < n) rowptr[gid] = basesh + s[tid] - v;
}

__global__ __launch_bounds__(256) void scatter_k(const int* __restrict__ ei,
                                                 const int* __restrict__ rowptr,
                                                 int* __restrict__ cursor,
                                                 int* __restrict__ csr_src) {
    int e = blockIdx.x * blockDim.x + threadIdx.x;
    if (e >= ET_) return;
    int s, d;
    if (e < EE) { s = ei[e]; d = ei[EE + e]; } else { s = e - EE; d = e - EE; }
    int pos = atomicAdd(&cursor[d], 1);
    csr_src[rowptr[d] + pos] = s;
}

// ---------------- bf16 MFMA GEMM, dbuf + LDS epilogue + fused attn-prep ----------------
// 1-D grid with XCD-pinning swizzle: the 4 col-blocks of each A-panel get
// block IDs congruent mod 8 -> same XCD -> A-panel fetched once per XCD.

__global__ __launch_bounds__(256) void gemm_bf16(const short* __restrict__ A,
                                                 const short* __restrict__ Wt,
                                                 const float* __restrict__ biasLin,
                                                 const float* __restrict__ attS,
                                                 const float* __restrict__ attD,
                                                 short* __restrict__ XLb,
                                                 short* __restrict__ Hlinb,
                                                 float* __restrict__ AS,
                                                 float* __restrict__ AD,
                                                 int M, int K) {
    __shared__ short smem[4][128 * 32];     // As0|As1|Bs0|Bs1, aliased as C-tile after loop
    const int NPX = (M + 127) >> 7;
    int px, yy;
    {
        const int bid = blockIdx.x;
        const int full = (NPX >> 3) << 5;   // 8-panel groups x 4 col-blocks
        if (bid < full) {
            const int grp = bid >> 5, wq = bid & 31;
            px = grp * 8 + (wq & 7);
            yy = wq >> 3;
        } else {
            const int rem = NPX & 7;
            const int r = bid - full;
            px = (NPX & ~7) + r % rem;
            yy = r / rem;
        }
    }
    const int tid = threadIdx.x;
    const int lane = tid & 63;
    const int wid = tid >> 6;
    const int bm = px * 128;
    const int col0 = yy * 128;
    const int wr = wid >> 1, wc = wid & 1;

    f32x4 acc[4][4];
#pragma unroll
    for (int i = 0; i < 4; ++i)
#pragma unroll
        for (int j = 0; j < 4; ++j) acc[i][j] = (f32x4){0.f, 0.f, 0.f, 0.f};

    const int lrow = lane & 15, lk = lane >> 4;

    auto stage = [&](int b, int kk) {
#pragma unroll
        for (int it = 0; it < 2; ++it) {
            const int flat = tid + it * 256;
            const int row = flat >> 2, slot = flat & 3;
            const int ss = slot ^ (row & 3);
            int ar = bm + row; ar = (ar < M) ? ar : (M - 1);
            GL16(A + (size_t)ar * K + kk + ss * 8, &smem[b][flat * 8]);
            GL16(Wt + (size_t)(col0 + row) * K + kk + ss * 8, &smem[2 + b][flat * 8]);
        }
    };

    stage(0, 0);
    int cur = 0;
    for (int k0 = 0; k0 < K; k0 += 32) {
        __syncthreads();
        if (k0 + 32 < K) stage(cur ^ 1, k0 + 32);
        bf16x8 af[4], bfr[4];
#pragma unroll
        for (int mi = 0; mi < 4; ++mi) {
            const int r = wr * 64 + mi * 16 + lrow;
            af[mi] = *(const bf16x8*)(&smem[cur][(r * 4 + (lk ^ (r & 3))) * 8]);
        }
#pragma unroll
        for (int ni = 0; ni < 4; ++ni) {
            const int c = wc * 64 + ni * 16 + lrow;
            bfr[ni] = *(const bf16x8*)(&smem[2 + cur][(c * 4 + (lk ^ (c & 3))) * 8]);
        }
#pragma unroll
        for (int mi = 0; mi < 4; ++mi)
#pragma unroll
            for (int ni = 0; ni < 4; ++ni)
                acc[mi][ni] = __builtin_amdgcn_mfma_f32_16x16x32_bf16(af[mi], bfr[ni], acc[mi][ni], 0, 0, 0);
        cur ^= 1;
    }

    __syncthreads();                        // reuse smem as C-tile [128][128] bf16, XOR-swizzled
    short* Ct = &smem[0][0];
    const bool isLin = (col0 >= 256);
    float bni[4] = {0.f, 0.f, 0.f, 0.f};
    if (isLin) {
#pragma unroll
        for (int ni = 0; ni < 4; ++ni)
            bni[ni] = biasLin[col0 - 256 + wc * 64 + ni * 16 + lrow];
    }
    const int lrow4 = lk * 4;
#pragma unroll
    for (int mi = 0; mi < 4; ++mi) {
#pragma unroll
        for (int ni = 0; ni < 4; ++ni) {
            const int col_l = wc * 64 + ni * 16 + lrow;
#pragma unroll
            for (int rr = 0; rr < 4; ++rr) {
                const int row_l = wr * 64 + mi * 16 + lrow4 + rr;
                const int idx = (row_l * 128 + col_l) ^ (((row_l >> 2) & 3) << 4);
                Ct[idx] = f2bf(acc[mi][ni][rr] + bni[ni]);
            }
        }
    }
    __syncthreads();

    short* outp = isLin ? Hlinb : XLb;
    const int gcol0 = isLin ? (col0 - 256) : col0;
    const int seg = tid & 15;
    float4 sA0, sA1, sD0, sD1;
    if (!isLin) {
        sA0 = *(const float4*)(attS + col0 + seg * 8);
        sA1 = *(const float4*)(attS + col0 + seg * 8 + 4);
        sD0 = *(const float4*)(attD + col0 + seg * 8);
        sD1 = *(const float4*)(attD + col0 + seg * 8 + 4);
    }
#pragma unroll
    for (int rr8 = 0; rr8 < 8; ++rr8) {
        const int flat = tid + rr8 * 256;
        const int row = flat >> 4;
        const int sidx = (row * 128 + seg * 8) ^ (((row >> 2) & 3) << 4);
        const int grow = bm + row;
        bf16x8 vv = *(const bf16x8*)(Ct + sidx);
        if (grow < M)
            *(bf16x8*)(outp + (size_t)grow * 256 + gcol0 + seg * 8) = vv;
        if (!isLin) {
            float f0 = bfs(vv[0]), f1 = bfs(vv[1]), f2 = bfs(vv[2]), f3 = bfs(vv[3]);
            float f4 = bfs(vv[4]), f5 = bfs(vv[5]), f6 = bfs(vv[6]), f7 = bfs(vv[7]);
            float sp = f0 * sA0.x + f1 * sA0.y + f2 * sA0.z + f3 * sA0.w
                     + f4 * sA1.x + f5 * sA1.y + f6 * sA1.z + f7 * sA1.w;
            float dp = f0 * sD0.x + f1 * sD0.y + f2 * sD0.z + f3 * sD0.w
                     + f4 * sD1.x + f5 * sD1.y + f6 * sD1.z + f7 * sD1.w;
            sp += __shfl_xor(sp, 1); dp += __shfl_xor(dp, 1);
            sp += __shfl_xor(sp, 2); dp += __shfl_xor(dp, 2);
            sp += __shfl_xor(sp, 4); dp += __shfl_xor(dp, 4);
            if ((seg & 7) == 0 && grow < M) {
                const int hh = (col0 >> 6) + (seg >> 3);
                AS[grow * 4 + hh] = sp;
                AD[grow * 4 + hh] = dp;
            }
        }
    }
}

// ---------------- shared GAT-aggregation core (wave per node, simple 2-edge gather) ----------------

__device__ __forceinline__ void agg_core(const short* __restrict__ XLb,
                                         const float* __restrict__ AS,
                                         const float4 ad4,
                                         int rs, int deg,
                                         const int* __restrict__ csr_src,
                                         int w, int lane,
                                         int (*sIdx)[64], float (*sExT)[4][72],
                                         float4& acc0, float4& acc1, float& denOut,
                                         int half, int l32, int ch0, int h) {
    float d0 = 0.f, d1 = 0.f, d2 = 0.f, d3 = 0.f;

    if (deg <= 64) {
        int sv = 0;
        float c0 = -1e30f, c1 = -1e30f, c2 = -1e30f, c3 = -1e30f;
        if (lane < deg) {
            sv = csr_src[rs + lane];
            float4 a = *(const float4*)(AS + sv * 4);
            c0 = lrelu_(a.x + ad4.x); c1 = lrelu_(a.y + ad4.y);
            c2 = lrelu_(a.z + ad4.z); c3 = lrelu_(a.w + ad4.w);
        }
        float m0 = c0, m1 = c1, m2 = c2, m3 = c3;
#pragma unroll
        for (int off = 32; off > 0; off >>= 1) {
            m0 = fmaxf(m0, __shfl_xor(m0, off));
            m1 = fmaxf(m1, __shfl_xor(m1, off));
            m2 = fmaxf(m2, __shfl_xor(m2, off));
            m3 = fmaxf(m3, __shfl_xor(m3, off));
        }
        float e0 = 0.f, e1 = 0.f, e2 = 0.f, e3 = 0.f;
        if (lane < deg) {
            e0 = __expf(c0 - m0); e1 = __expf(c1 - m1);
            e2 = __expf(c2 - m2); e3 = __expf(c3 - m3);
        }
        sIdx[w][lane] = sv;
        sExT[w][0][lane] = e0; sExT[w][1][lane] = e1;
        sExT[w][2][lane] = e2; sExT[w][3][lane] = e3;
        d0 = e0; d1 = e1; d2 = e2; d3 = e3;
        __builtin_amdgcn_wave_barrier();

        const int cpad = (deg + 1) & ~1;
        for (int j = 0; j < cpad; j += 2) {
            int jj = j + half;
            int s = sIdx[w][jj];
            float e = sExT[w][h][jj];
            const uint4 q = *(const uint4*)(XLb + (size_t)s * 256 + ch0);
            acc0.x += e * bflo(q.x); acc0.y += e * bfhi(q.x);
            acc0.z += e * bflo(q.y); acc0.w += e * bfhi(q.y);
            acc1.x += e * bflo(q.z); acc1.y += e * bfhi(q.z);
            acc1.z += e * bflo(q.w); acc1.w += e * bfhi(q.w);
        }
    } else {
        float m0 = -1e30f, m1 = -1e30f, m2 = -1e30f, m3 = -1e30f;
        for (int base = 0; base < deg; base += 64) {
            int idx = base + lane;
            if (idx < deg) {
                int s = csr_src[rs + idx];
                float4 a = *(const float4*)(AS + s * 4);
                m0 = fmaxf(m0, lrelu_(a.x + ad4.x));
                m1 = fmaxf(m1, lrelu_(a.y + ad4.y));
                m2 = fmaxf(m2, lrelu_(a.z + ad4.z));
                m3 = fmaxf(m3, lrelu_(a.w + ad4.w));
            }
        }
#pragma unroll
        for (int off = 32; off > 0; off >>= 1) {
            m0 = fmaxf(m0, __shfl_xor(m0, off));
            m1 = fmaxf(m1, __shfl_xor(m1, off));
            m2 = fmaxf(m2, __shfl_xor(m2, off));
            m3 = fmaxf(m3, __shfl_xor(m3, off));
        }
        for (int base = 0; base < deg; base += 64) {
            int cnt = deg - base; if (cnt > 64) cnt = 64;
            int idx = base + lane;
            int sv = 0;
            float e0 = 0.f, e1 = 0.f, e2 = 0.f, e3 = 0.f;
            if (idx < deg) {
                sv = csr_src[rs + idx];
                float4 a = *(const float4*)(AS + sv * 4);
                e0 = __expf(lrelu_(a.x + ad4.x) - m0);
                e1 = __expf(lrelu_(a.y + ad4.y) - m1);
                e2 = __expf(lrelu_(a.z + ad4.z) - m2);
                e3 = __expf(lrelu_(a.w + ad4.w) - m3);
            }
            sIdx[w][lane] = sv;
            sExT[w][0][lane] = e0; sExT[w][1][lane] = e1;
            sExT[w][2][lane] = e2; sExT[w][3][lane] = e3;
            d0 += e0; d1 += e1; d2 += e2; d3 += e3;
            __builtin_amdgcn_wave_barrier();
            int cpad = (cnt + 1) & ~1;
            for (int j = 0; j < cpad; j += 2) {
                int jj = j + half;
                int s = sIdx[w][jj];
                float e = sExT[w][h][jj];
                const uint4 q = *(const uint4*)(XLb + (size_t)s * 256 + ch0);
                acc0.x += e * bflo(q.x); acc0.y += e * bfhi(q.x);
                acc0.z += e * bflo(q.y); acc0.w += e * bfhi(q.y);
                acc1.x += e * bflo(q.z); acc1.y += e * bfhi(q.z);
                acc1.z += e * bflo(q.w); acc1.w += e * bfhi(q.w);
            }
            __builtin_amdgcn_wave_barrier();
        }
    }

    acc0.x += __shfl_xor(acc0.x, 32); acc0.y += __shfl_xor(acc0.y, 32);
    acc0.z += __shfl_xor(acc0.z, 32); acc0.w += __shfl_xor(acc0.w, 32);
    acc1.x += __shfl_xor(acc1.x, 32); acc1.y += __shfl_xor(acc1.y, 32);
    acc1.z += __shfl_xor(acc1.z, 32); acc1.w += __shfl_xor(acc1.w, 32);
#pragma unroll
    for (int off = 32; off > 0; off >>= 1) {
        d0 += __shfl_xor(d0, off); d1 += __shfl_xor(d1, off);
        d2 += __shfl_xor(d2, off); d3 += __shfl_xor(d3, off);
    }
    denOut = (h == 0) ? d0 : (h == 1) ? d1 : (h == 2) ? d2 : d3;
}

// ---------------- layer-0 aggregation: write Hb (bf16) ----------------

__global__ __launch_bounds__(256, 8) void gat_agg0(const short* __restrict__ XLb,
                                                   const float* __restrict__ AS,
                                                   const float* __restrict__ AD,
                                                   const int* __restrict__ rowptr,
                                                   const int* __restrict__ degarr,
                                                   const int* __restrict__ csr_src,
                                                   const float* __restrict__ cb,
                                                   const short* __restrict__ Hlinb,
                                                   short* __restrict__ Hb, int n_nodes) {
    __shared__ int   sIdx[4][64];
    __shared__ float sExT[4][4][72];
    const int tid = threadIdx.x;
    const int lane = tid & 63;
    const int w = tid >> 6;
    const int n = blockIdx.x * 4 + w;
    if (n >= n_nodes) return;

    const int rs = rowptr[n];
    const int deg = degarr[n];
    const float4 ad4 = *(const float4*)(AD + n * 4);
    const int half = lane >> 5, l32 = lane & 31, ch0 = l32 * 8, h = l32 >> 3;

    float4 acc0 = make_float4(0.f, 0.f, 0.f, 0.f);
    float4 acc1 = make_float4(0.f, 0.f, 0.f, 0.f);
    float den;
    agg_core(XLb, AS, ad4, rs, deg, csr_src, w, lane, sIdx, sExT, acc0, acc1, den,
             half, l32, ch0, h);
    float inv = 1.f / (den + 1e-16f);

    if (lane < 32) {
        size_t o = (size_t)n * 256 + ch0;
        uint4 hq = *(const uint4*)(Hlinb + o);
        float4 cba = *(const float4*)(cb + ch0);
        float4 cbb = *(const float4*)(cb + ch0 + 4);
        float v0 = elu_(acc0.x * inv + cba.x + bflo(hq.x));
        float v1 = elu_(acc0.y * inv + cba.y + bfhi(hq.x));
        float v2 = elu_(acc0.z * inv + cba.z + bflo(hq.y));
        float v3 = elu_(acc0.w * inv + cba.w + bfhi(hq.y));
        float v4 = elu_(acc1.x * inv + cbb.x + bflo(hq.z));
        float v5 = elu_(acc1.y * inv + cbb.y + bfhi(hq.z));
        float v6 = elu_(acc1.z * inv + cbb.z + bflo(hq.w));
        float v7 = elu_(acc1.w * inv + cbb.w + bfhi(hq.w));
        uint4 ov;
        ov.x = (unsigned)(unsigned short)f2bf(v0) | ((unsigned)(unsigned short)f2bf(v1) << 16);
        ov.y = (unsigned)(unsigned short)f2bf(v2) | ((unsigned)(unsigned short)f2bf(v3) << 16);
        ov.z = (unsigned)(unsigned short)f2bf(v4) | ((unsigned)(unsigned short)f2bf(v5) << 16);
        ov.w = (unsigned)(unsigned short)f2bf(v6) | ((unsigned)(unsigned short)f2bf(v7) << 16);
        *(uint4*)(Hb + o) = ov;
    }
}

// ---------------- layer-1 aggregation: fused layer-2 projections ----------------

__global__ __launch_bounds__(256, 8) void gat_agg1(const short* __restrict__ XLb,
                                                   const float* __restrict__ AS,
                                                   const float* __restrict__ AD,
                                                   const int* __restrict__ rowptr,
                                                   const int* __restrict__ degarr,
                                                   const int* __restrict__ csr_src,
                                                   const float* __restrict__ cb,
                                                   const short* __restrict__ Hlinb,
                                                   const float* __restrict__ cW2,
                                                   const float* __restrict__ lW2,
                                                   const float* __restrict__ lb2,
                                                   float* __restrict__ XL2,
                                                   float* __restrict__ LIN2, int n_nodes) {
    __shared__ int   sIdx[4][64];
    __shared__ float sExT[4][4][72];
    const int tid = threadIdx.x;
    const int lane = tid & 63;
    const int w = tid >> 6;
    const int n = blockIdx.x * 4 + w;
    if (n >= n_nodes) return;

    const int rs = rowptr[n];
    const int deg = degarr[n];
    const float4 ad4 = *(const float4*)(AD + n * 4);
    const int half = lane >> 5, l32 = lane & 31, ch0 = l32 * 8, h = l32 >> 3;

    float4 acc0 = make_float4(0.f, 0.f, 0.f, 0.f);
    float4 acc1 = make_float4(0.f, 0.f, 0.f, 0.f);
    float den;
    agg_core(XLb, AS, ad4, rs, deg, csr_src, w, lane, sIdx, sExT, acc0, acc1, den,
             half, l32, ch0, h);
    float inv = 1.f / (den + 1e-16f);

    float p0 = 0.f, p1 = 0.f, p2 = 0.f, p3 = 0.f, pl = 0.f;
    if (lane < 32) {
        size_t o = (size_t)n * 256 + ch0;
        uint4 hq = *(const uint4*)(Hlinb + o);
        float4 cba = *(const float4*)(cb + ch0);
        float4 cbb = *(const float4*)(cb + ch0 + 4);
        float vv[8];
        vv[0] = elu_(acc0.x * inv + cba.x + bflo(hq.x));
        vv[1] = elu_(acc0.y * inv + cba.y + bfhi(hq.x));
        vv[2] = elu_(acc0.z * inv + cba.z + bflo(hq.y));
        vv[3] = elu_(acc0.w * inv + cba.w + bfhi(hq.y));
        vv[4] = elu_(acc1.x * inv + cbb.x + bflo(hq.z));
        vv[5] = elu_(acc1.y * inv + cbb.y + bfhi(hq.z));
        vv[6] = elu_(acc1.z * inv + cbb.z + bflo(hq.w));
        vv[7] = elu_(acc1.w * inv + cbb.w + bfhi(hq.w));
        float4 lwa = *(const float4*)(lW2 + ch0);
        float4 lwb = *(const float4*)(lW2 + ch0 + 4);
        const float lw[8] = {lwa.x, lwa.y, lwa.z, lwa.w, lwb.x, lwb.y, lwb.z, lwb.w};
#pragma unroll
        for (int j = 0; j < 8; ++j) {
            float4 wv = *(const float4*)(cW2 + (ch0 + j) * 4);
            p0 += vv[j] * wv.x; p1 += vv[j] * wv.y;
            p2 += vv[j] * wv.z; p3 += vv[j] * wv.w;
            pl += vv[j] * lw[j];
        }
    }
#pragma unroll
    for (int off = 16; off > 0; off >>= 1) {
        p0 += __shfl_xor(p0, off); p1 += __shfl_xor(p1, off);
        p2 += __shfl_xor(p2, off); p3 += __shfl_xor(p3, off);
        pl += __shfl_xor(pl, off);
    }
    if (lane == 0) {
        *(float4*)(XL2 + n * 4) = make_float4(p0, p1, p2, p3);
        LIN2[n] = pl + lb2[0];
    }
}

// ---------------- layer 2 aggregation (deg<=64 single-pass fast path) ----------------

__global__ __launch_bounds__(256, 8) void l2_agg(const float* __restrict__ XL2,
                                                 const float* __restrict__ LIN2,
                                                 const float* __restrict__ cas2,
                                                 const float* __restrict__ cad2,
                                                 const float* __restrict__ cb2,
                                                 const int* __restrict__ rowptr,
                                                 const int* __restrict__ degarr,
                                                 const int* __restrict__ csr_src,
                                                 float* __restrict__ out, int n_nodes) {
    int n = (blockIdx.x * blockDim.x + threadIdx.x) >> 6;
    int lane = threadIdx.x & 63;
    if (n >= n_nodes) return;
    int rs = rowptr[n];
    int deg = degarr[n];
    float4 xn = *(const float4*)(XL2 + n * 4);
    float cs0 = cas2[0], cs1 = cas2[1], cs2 = cas2[2], cs3 = cas2[3];
    float cd0 = cad2[0], cd1 = cad2[1], cd2 = cad2[2], cd3 = cad2[3];
    float ad0 = xn.x * cd0, ad1 = xn.y * cd1, ad2 = xn.z * cd2, ad3 = xn.w * cd3;

    float d0 = 0.f, d1 = 0.f, d2 = 0.f, d3 = 0.f;
    float t0 = 0.f, t1 = 0.f, t2 = 0.f, t3 = 0.f;

    if (deg <= 64) {
        float4 xs = make_float4(0.f, 0.f, 0.f, 0.f);
        float c0 = -1e30f, c1 = -1e30f, c2 = -1e30f, c3 = -1e30f;
        if (lane < deg) {
            int s = csr_src[rs + lane];
            xs = *(const float4*)(XL2 + s * 4);
            c0 = lrelu_(xs.x * cs0 + ad0); c1 = lrelu_(xs.y * cs1 + ad1);
            c2 = lrelu_(xs.z * cs2 + ad2); c3 = lrelu_(xs.w * cs3 + ad3);
        }
        float m0 = c0, m1 = c1, m2 = c2, m3 = c3;
#pragma unroll
        for (int off = 32; off > 0; off >>= 1) {
            m0 = fmaxf(m0, __shfl_xor(m0, off));
            m1 = fmaxf(m1, __shfl_xor(m1, off));
            m2 = fmaxf(m2, __shfl_xor(m2, off));
            m3 = fmaxf(m3, __shfl_xor(m3, off));
        }
        if (lane < deg) {
            float e0 = __expf(c0 - m0), e1 = __expf(c1 - m1);
            float e2 = __expf(c2 - m2), e3 = __expf(c3 - m3);
            d0 = e0; d1 = e1; d2 = e2; d3 = e3;
            t0 = e0 * xs.x; t1 = e1 * xs.y; t2 = e2 * xs.z; t3 = e3 * xs.w;
        }
    } else {
        int re = rs + deg;
        float m0 = -1e30f, m1 = -1e30f, m2 = -1e30f, m3 = -1e30f;
        for (int i = rs + lane; i < re; i += 64) {
            int s = csr_src[i];
            float4 xs = *(const float4*)(XL2 + s * 4);
            m0 = fmaxf(m0, lrelu_(xs.x * cs0 + ad0));
            m1 = fmaxf(m1, lrelu_(xs.y * cs1 + ad1));
            m2 = fmaxf(m2, lrelu_(xs.z * cs2 + ad2));
            m3 = fmaxf(m3, lrelu_(xs.w * cs3 + ad3));
        }
#pragma unroll
        for (int off = 32; off > 0; off >>= 1) {
            m0 = fmaxf(m0, __shfl_xor(m0, off));
            m1 = fmaxf(m1, __shfl_xor(m1, off));
            m2 = fmaxf(m2, __shfl_xor(m2, off));
            m3 = fmaxf(m3, __shfl_xor(m3, off));
        }
        for (int i = rs + lane; i < re; i += 64) {
            int s = csr_src[i];
            float4 xs = *(const float4*)(XL2 + s * 4);
            float e0 = __expf(lrelu_(xs.x * cs0 + ad0) - m0);
            float e1 = __expf(lrelu_(xs.y * cs1 + ad1) - m1);
            float e2 = __expf(lrelu_(xs.z * cs2 + ad2) - m2);
            float e3 = __expf(lrelu_(xs.w * cs3 + ad3) - m3);
            d0 += e0; d1 += e1; d2 += e2; d3 += e3;
            t0 += e0 * xs.x; t1 += e1 * xs.y; t2 += e2 * xs.z; t3 += e3 * xs.w;
        }
    }
#pragma unroll
    for (int off = 32; off > 0; off >>= 1) {
        d0 += __shfl_xor(d0, off); d1 += __shfl_xor(d1, off);
        d2 += __shfl_xor(d2, off); d3 += __shfl_xor(d3, off);
        t0 += __shfl_xor(t0, off); t1 += __shfl_xor(t1, off);
        t2 += __shfl_xor(t2, off); t3 += __shfl_xor(t3, off);
    }
    if (lane == 0) {
        float r = 0.25f * (t0 / (d0 + 1e-16f) + t1 / (d1 + 1e-16f) +
                           t2 / (d2 + 1e-16f) + t3 / (d3 + 1e-16f));
        out[n] = r + cb2[0] + LIN2[n];
    }
}

// ---------------- launch ----------------

extern "C" void kernel_launch(void* const* d_in, const int* in_sizes, int n_in,
                              void* d_out, int out_size, void* d_ws, size_t ws_size,
                              hipStream_t stream) {
    const float* x    = (const float*)d_in[0];
    const int*   ei   = (const int*)d_in[1];
    const float* cW0  = (const float*)d_in[3];
    const float* cas0 = (const float*)d_in[4];
    const float* cad0 = (const float*)d_in[5];
    const float* cb0  = (const float*)d_in[6];
    const float* lW0  = (const float*)d_in[7];
    const float* lb0  = (const float*)d_in[8];
    const float* cW1  = (const float*)d_in[9];
    const float* cas1 = (const float*)d_in[10];
    const float* cad1 = (const float*)d_in[11];
    const float* cb1  = (const float*)d_in[12];
    const float* lW1  = (const float*)d_in[13];
    const float* lb1  = (const float*)d_in[14];
    const float* cW2  = (const float*)d_in[15];
    const float* cas2 = (const float*)d_in[16];
    const float* cad2 = (const float*)d_in[17];
    const float* cb2  = (const float*)d_in[18];
    const float* lW2  = (const float*)d_in[19];
    const float* lb2  = (const float*)d_in[20];
    float* out = (float*)d_out;

    // workspace layout (~97 MB)
    short* xb    = (short*)d_ws;                 // 6.4M bf16
    short* XLb   = xb + 6400000;                 // 12.8M bf16
    short* HAb   = XLb + 12800000;
    short* Hlinb = HAb + 12800000;               // 12.8M bf16
    short* Wt0   = Hlinb + 12800000;             // 512*128
    short* Wt1   = Wt0 + 65536;                  // 512*256
    float* AS    = (float*)(Wt1 + 131072);
    float* AD    = AS + 200000;
    float* XL2   = AD + 200000;
    float* LIN2  = XL2 + 200000;
    int* deg     = (int*)(LIN2 + NN);            // [NN]
    int* cursor  = deg + NN;                     // [NN]
    int* gcnt    = cursor + NN;                  // [4]
    int* rowptr  = gcnt + 4;                     // [NN]
    int* csr_src = rowptr + NN;                  // [ET_]

    dim3 b256(256);
    dim3 gEdges((ET_ + 255) / 256);
    dim3 gNodesWave((NN + 3) / 4);

    hipMemsetAsync(deg, 0, (2 * (size_t)NN + 4) * sizeof(int), stream);
    prep_all<<<dim3(10339), b256, 0, stream>>>(x, cW0, lW0, cW1, lW1, ei, deg, xb, Wt0, Wt1);
    alloc_scan<<<dim3((NN + 1023) / 1024), dim3(1024), 0, stream>>>(deg, rowptr, gcnt, NN);
    scatter_k<<<gEdges, b256, 0, stream>>>(ei, rowptr, cursor, csr_src);

    const int NPX = (NN + 127) / 128;            // 391 A-panels
    dim3 gemmGrid(NPX * 4);                      // 1-D, XCD-pinned decode in-kernel

    // layer 0 (GEMM computes XLb/Hlinb and AS/AD in one pass)
    gemm_bf16<<<gemmGrid, b256, 0, stream>>>(xb, Wt0, lb0, cas0, cad0, XLb, Hlinb, AS, AD, NN, 128);
    gat_agg0<<<gNodesWave, b256, 0, stream>>>(XLb, AS, AD, rowptr, deg, csr_src, cb0, Hlinb, HAb, NN);

    // layer 1 (+ fused layer-2 projections)
    gemm_bf16<<<gemmGrid, b256, 0, stream>>>(HAb, Wt1, lb1, cas1, cad1, XLb, Hlinb, AS, AD, NN, 256);
    gat_agg1<<<gNodesWave, b256, 0, stream>>>(XLb, AS, AD, rowptr, deg, csr_src, cb1, Hlinb,
                                              cW2, lW2, lb2, XL2, LIN2, NN);

    // layer 2 aggregation
    l2_agg<<<gNodesWave, b256, 0, stream>>>(XL2, LIN2, cas2, cad2, cb2, rowptr, deg, csr_src, out, NN);
}